// Round 2
// baseline (208.403 us; speedup 1.0000x reference)
//
#include <hip/hip_runtime.h>

// set_transform: out[i,j,q,e] = sum_{h,k} relu((x_j W1)[q,h,:]·(y_j W2)[k,h,:]/8)/128 * (y_i W34)[k,h,e]
// where W34[c, h*64+e] = sum_d W3[c,h*64+d] W4[h*64+d,e]  (fuses final @W4 into V-proj).
// All matmuls via bf16 hi/lo split MFMA (3 products: hh, hl, lh) -> ~1e-5 rel err vs fp32.
//
// Shapes: S=32 sets, N=128 items, C=512 d_model, H=8 heads, D=64.
//   stage P (prep):  split x,y -> bf16 hi/lo [4096][512]; W1T,W2T hi/lo [512][512]; W34T hi/lo [512][512]
//   stage B (proj):  Q,K -> [s][h][n][64] hi/lo ; VWT -> [(i*64+e)][h*128+n] hi/lo  ([2048][1024])
//   stage C (attn):  A  -> [(j*128+q)][(h*128+k)] hi/lo  ([4096][1024])  — ALIASED over x/y buffers
//   stage D (out):   single GEMM  [4096,1024] x [2048,1024]^T -> scatter to out[i,j,q,e]

#define MB (1u << 20)

typedef __attribute__((ext_vector_type(8))) short bf16x8;
typedef __attribute__((ext_vector_type(4))) float f32x4;

enum : size_t {
  OFF_XH  = 0,                       // later reused as A hi (attn output, 8MB spans XH+XL)
  OFF_XL  = OFF_XH  + 4 * MB,
  OFF_YH  = OFF_XL  + 4 * MB,        // later reused as A lo
  OFF_YL  = OFF_YH  + 4 * MB,
  OFF_W1H = OFF_YL  + 4 * MB,
  OFF_W1L = OFF_W1H + 512 * 1024,
  OFF_W2H = OFF_W1L + 512 * 1024,
  OFF_W2L = OFF_W2H + 512 * 1024,
  OFF_W3H = OFF_W2L + 512 * 1024,   // W34T hi
  OFF_W3L = OFF_W3H + 512 * 1024,   // W34T lo
  OFF_QH  = OFF_W3L + 512 * 1024,
  OFF_QL  = OFF_QH  + 4 * MB,
  OFF_KH  = OFF_QL  + 4 * MB,
  OFF_KL  = OFF_KH  + 4 * MB,
  OFF_VWH = OFF_KL  + 4 * MB,
  OFF_VWL = OFF_VWH + 4 * MB,
  WS_NEED = OFF_VWL + 4 * MB,       // 43 MB
  OFF_AH  = OFF_XH,                 // A hi/lo alias x/y split buffers (dead after proj_gemm)
  OFF_AL  = OFF_YH
};

__device__ __forceinline__ unsigned short f2bf(float f) {
  unsigned u = __builtin_bit_cast(unsigned, f);
  u += 0x7FFFu + ((u >> 16) & 1u);          // RNE
  return (unsigned short)(u >> 16);
}
__device__ __forceinline__ float bf2f(unsigned short h) {
  unsigned u = ((unsigned)h) << 16;
  return __builtin_bit_cast(float, u);
}
__device__ __forceinline__ void split2(float v, unsigned short& hi, unsigned short& lo) {
  hi = f2bf(v);
  lo = f2bf(v - bf2f(hi));
}

#define GLOAD_LDS16(g, l)                                                    \
  __builtin_amdgcn_global_load_lds(                                          \
      (const __attribute__((address_space(1))) void*)(g),                    \
      (__attribute__((address_space(3))) void*)(l), 16, 0, 0)

// ---------------------------------------------------------------------------
// prep: split x,y; transpose+split W1,W2; compute W34 = per-head W3@W4, transpose+split.
// grid = 7168 x 256 (block-aligned ranges; no intra-block divergence)
// ---------------------------------------------------------------------------
__global__ __launch_bounds__(256) void prep_all(
    const float* __restrict__ x, const float* __restrict__ y,
    const float* __restrict__ W1, const float* __restrict__ W2,
    const float* __restrict__ W3, const float* __restrict__ W4,
    unsigned short* xh, unsigned short* xl, unsigned short* yh, unsigned short* yl,
    unsigned short* w1h, unsigned short* w1l, unsigned short* w2h, unsigned short* w2l,
    unsigned short* w34h, unsigned short* w34l) {
  int idx = blockIdx.x * 256 + threadIdx.x;
  if (idx < 1048576) {                       // x,y split (float4 per thread)
    const float4* src; unsigned short *dh, *dl; int t;
    if (idx < 524288) { src = (const float4*)x; dh = xh; dl = xl; t = idx; }
    else              { src = (const float4*)y; dh = yh; dl = yl; t = idx - 524288; }
    float4 v = src[t];
    ushort4 hi, lo;
    split2(v.x, hi.x, lo.x); split2(v.y, hi.y, lo.y);
    split2(v.z, hi.z, lo.z); split2(v.w, hi.w, lo.w);
    *(ushort4*)&dh[t * 4] = hi;
    *(ushort4*)&dl[t * 4] = lo;
  } else if (idx < 1048576 + 524288) {       // W1,W2 transpose+split: out[n][c] = W[c][n]
    int t = idx - 1048576;
    const float* W; unsigned short *dh, *dl; int u;
    if (t < 262144) { W = W1; dh = w1h; dl = w1l; u = t; }
    else            { W = W2; dh = w2h; dl = w2l; u = t - 262144; }
    int n = u >> 9, c = u & 511;
    unsigned short hi, lo; split2(W[c * 512 + n], hi, lo);
    dh[u] = hi; dl[u] = lo;
  } else {                                   // W34T[(h*64+e)][c] = sum_d W3[c][h*64+d]*W4[h*64+d][e]
    int t = idx - 1572864;
    int c = t >> 9, he = t & 511;            // c wave-uniform -> W3 scalar broadcast, W4 coalesced in e
    int h = he >> 6, e = he & 63;
    float acc = 0.f;
#pragma unroll
    for (int d = 0; d < 64; ++d)
      acc += W3[c * 512 + h * 64 + d] * W4[(h * 64 + d) * 64 + e];
    unsigned short hi, lo; split2(acc, hi, lo);
    w34h[he * 512 + c] = hi;
    w34l[he * 512 + c] = lo;
  }
}

// ---------------------------------------------------------------------------
// Shared GEMM core: 128x128 output tile, 4 waves (2x2), K in 64-chunks.
// A,B row-major with k contiguous (NT form). hi/lo split -> 3 MFMAs/product.
// LDS: 4 x 16KB buffers (Ahi,Alo,Bhi,Blo); wave w stages buffer w via global_load_lds.
// ---------------------------------------------------------------------------
template <int KTILES, typename EPI>
__device__ __forceinline__ void gemm128(
    const unsigned short* __restrict__ Ahi, const unsigned short* __restrict__ Alo,
    const unsigned short* __restrict__ Bhi, const unsigned short* __restrict__ Blo,
    int row_stride_bytes, EPI&& epi) {
  __shared__ unsigned short sAhi[128 * 64], sAlo[128 * 64];
  __shared__ unsigned short sBhi[128 * 64], sBlo[128 * 64];
  const int tid  = threadIdx.x;
  const int lane = tid & 63;
  const int wid  = tid >> 6;
  const int wm   = wid >> 1, wn = wid & 1;
  const int lr   = lane & 15;
  const int lk   = (lane >> 4) * 8;

  f32x4 acc[4][4];
#pragma unroll
  for (int i = 0; i < 4; ++i)
#pragma unroll
    for (int j = 0; j < 4; ++j) acc[i][j] = (f32x4){0.f, 0.f, 0.f, 0.f};

  const unsigned short* gsrc = (wid == 0) ? Ahi : (wid == 1) ? Alo : (wid == 2) ? Bhi : Blo;
  unsigned short* lbuf       = (wid == 0) ? sAhi : (wid == 1) ? sAlo : (wid == 2) ? sBhi : sBlo;

  for (int kc = 0; kc < KTILES; ++kc) {
    if (kc) __syncthreads();
    const char* gbase = (const char*)gsrc + kc * 128;   // 64 bf16 = 128B col window
#pragma unroll
    for (int i = 0; i < 16; ++i) {                      // 16 x 1KB per wave = 16KB buffer
      int off = i * 1024 + lane * 16;
      int row = off >> 7, cb = off & 127;
      GLOAD_LDS16(gbase + (size_t)row * row_stride_bytes + cb, (char*)lbuf + i * 1024);
    }
    __syncthreads();
#pragma unroll
    for (int ks = 0; ks < 2; ++ks) {
      bf16x8 ah[4], al[4], bh[4], bl[4];
#pragma unroll
      for (int f = 0; f < 4; ++f) {
        int aoff = (wm * 64 + f * 16 + lr) * 64 + ks * 32 + lk;
        ah[f] = *(const bf16x8*)&sAhi[aoff];
        al[f] = *(const bf16x8*)&sAlo[aoff];
        int boff = (wn * 64 + f * 16 + lr) * 64 + ks * 32 + lk;
        bh[f] = *(const bf16x8*)&sBhi[boff];
        bl[f] = *(const bf16x8*)&sBlo[boff];
      }
#pragma unroll
      for (int fm = 0; fm < 4; ++fm)
#pragma unroll
        for (int fn = 0; fn < 4; ++fn) {
          acc[fm][fn] = __builtin_amdgcn_mfma_f32_16x16x32_bf16(ah[fm], bh[fn], acc[fm][fn], 0, 0, 0);
          acc[fm][fn] = __builtin_amdgcn_mfma_f32_16x16x32_bf16(ah[fm], bl[fn], acc[fm][fn], 0, 0, 0);
          acc[fm][fn] = __builtin_amdgcn_mfma_f32_16x16x32_bf16(al[fm], bh[fn], acc[fm][fn], 0, 0, 0);
        }
    }
  }
  // C/D layout (m89-verified): col = lane&15, row = (lane>>4)*4 + reg
#pragma unroll
  for (int fm = 0; fm < 4; ++fm)
#pragma unroll
    for (int fn = 0; fn < 4; ++fn)
#pragma unroll
      for (int r = 0; r < 4; ++r) {
        int ml = wm * 64 + fm * 16 + (lane >> 4) * 4 + r;
        int nl = wn * 64 + fn * 16 + lr;
        epi(ml, nl, acc[fm][fn][r]);
      }
}

// ---------------------------------------------------------------------------
// proj: z=0 Q=x@W1T, z=1 K=y@W2T, z=2 VW=y@W34T.  M=4096,N=512,K=512.
// grid (32, 4, 3) x 256
// ---------------------------------------------------------------------------
__global__ __launch_bounds__(256) void proj_gemm(
    const unsigned short* __restrict__ xh, const unsigned short* __restrict__ xl,
    const unsigned short* __restrict__ yh, const unsigned short* __restrict__ yl,
    const unsigned short* __restrict__ w1h, const unsigned short* __restrict__ w1l,
    const unsigned short* __restrict__ w2h, const unsigned short* __restrict__ w2l,
    const unsigned short* __restrict__ w34h, const unsigned short* __restrict__ w34l,
    unsigned short* qh, unsigned short* ql,
    unsigned short* kh, unsigned short* kl,
    unsigned short* vwh, unsigned short* vwl) {
  const int mt = blockIdx.x, nt = blockIdx.y, z = blockIdx.z;
  const unsigned short *Ahi, *Alo, *Bhi, *Blo;
  if (z == 0)      { Ahi = xh; Alo = xl; Bhi = w1h;  Blo = w1l; }
  else if (z == 1) { Ahi = yh; Alo = yl; Bhi = w2h;  Blo = w2l; }
  else             { Ahi = yh; Alo = yl; Bhi = w34h; Blo = w34l; }
  Ahi += (size_t)mt * 128 * 512; Alo += (size_t)mt * 128 * 512;
  Bhi += (size_t)nt * 128 * 512; Blo += (size_t)nt * 128 * 512;

  gemm128<8>(Ahi, Alo, Bhi, Blo, 1024, [&](int ml, int nl, float v) {
    int row = mt * 128 + ml;          // (s, item)
    int col = nt * 128 + nl;          // (h, d|e)
    int s = row >> 7, n = row & 127;
    int h = col >> 6, d = col & 63;
    unsigned short hi, lo; split2(v, hi, lo);
    if (z == 0)      { int a = ((s * 8 + h) * 128 + n) * 64 + d; qh[a] = hi; ql[a] = lo; }
    else if (z == 1) { int a = ((s * 8 + h) * 128 + n) * 64 + d; kh[a] = hi; kl[a] = lo; }
    else             { int a = (s * 64 + d) * 1024 + h * 128 + n; vwh[a] = hi; vwl[a] = lo; }
  });
}

// ---------------------------------------------------------------------------
// attn: per (s,h): relu(Q K^T / 8)/128 -> A[(s*128+q)][(h*128+k)].  M=N=128,K=64.
// grid (32, 8) x 256
// ---------------------------------------------------------------------------
__global__ __launch_bounds__(256) void attn_gemm(
    const unsigned short* __restrict__ qh, const unsigned short* __restrict__ ql,
    const unsigned short* __restrict__ kh, const unsigned short* __restrict__ kl,
    unsigned short* ah, unsigned short* al) {
  const int s = blockIdx.x, h = blockIdx.y;
  const size_t off = (size_t)(s * 8 + h) * 128 * 64;
  gemm128<1>(qh + off, ql + off, kh + off, kl + off, 128, [&](int ml, int nl, float v) {
    v = fmaxf(v * 0.125f, 0.f) * (1.0f / 128.0f);
    unsigned short hi, lo; split2(v, hi, lo);
    int a = (s * 128 + ml) * 1024 + h * 128 + nl;
    ah[a] = hi; al[a] = lo;
  });
}

// ---------------------------------------------------------------------------
// out: [4096,1024] @ [2048,1024]^T -> out[i,j,q,e].  M=4096,N=2048,K=1024.
// grid (32, 16) x 256
// ---------------------------------------------------------------------------
__global__ __launch_bounds__(256) void out_gemm(
    const unsigned short* __restrict__ ah, const unsigned short* __restrict__ al,
    const unsigned short* __restrict__ vwh, const unsigned short* __restrict__ vwl,
    float* __restrict__ out) {
  const int mt = blockIdx.x, nt = blockIdx.y;
  gemm128<16>(ah + (size_t)mt * 128 * 1024, al + (size_t)mt * 128 * 1024,
              vwh + (size_t)nt * 128 * 1024, vwl + (size_t)nt * 128 * 1024, 2048,
              [&](int ml, int nl, float v) {
                int row = mt * 128 + ml;    // (j, q)
                int col = nt * 128 + nl;    // (i, e)
                int i = col >> 6, e = col & 63;
                int j = row >> 7, q = row & 127;
                out[(size_t)(((i * 32 + j) * 128 + q)) * 64 + e] = v;
              });
}

// ---------------------------------------------------------------------------
extern "C" void kernel_launch(void* const* d_in, const int* in_sizes, int n_in,
                              void* d_out, int out_size, void* d_ws, size_t ws_size,
                              hipStream_t stream) {
  const float* x  = (const float*)d_in[0];
  const float* y  = (const float*)d_in[1];
  const float* W1 = (const float*)d_in[2];
  const float* W2 = (const float*)d_in[3];
  const float* W3 = (const float*)d_in[4];
  const float* W4 = (const float*)d_in[5];
  float* out = (float*)d_out;
  char* ws = (char*)d_ws;

  unsigned short* xh  = (unsigned short*)(ws + OFF_XH);
  unsigned short* xl  = (unsigned short*)(ws + OFF_XL);
  unsigned short* yh  = (unsigned short*)(ws + OFF_YH);
  unsigned short* yl  = (unsigned short*)(ws + OFF_YL);
  unsigned short* w1h = (unsigned short*)(ws + OFF_W1H);
  unsigned short* w1l = (unsigned short*)(ws + OFF_W1L);
  unsigned short* w2h = (unsigned short*)(ws + OFF_W2H);
  unsigned short* w2l = (unsigned short*)(ws + OFF_W2L);
  unsigned short* w3h = (unsigned short*)(ws + OFF_W3H);
  unsigned short* w3l = (unsigned short*)(ws + OFF_W3L);
  unsigned short* qh  = (unsigned short*)(ws + OFF_QH);
  unsigned short* ql  = (unsigned short*)(ws + OFF_QL);
  unsigned short* kh  = (unsigned short*)(ws + OFF_KH);
  unsigned short* kl  = (unsigned short*)(ws + OFF_KL);
  unsigned short* vwh = (unsigned short*)(ws + OFF_VWH);
  unsigned short* vwl = (unsigned short*)(ws + OFF_VWL);
  unsigned short* ah  = (unsigned short*)(ws + OFF_AH);   // aliases xh/xl region (dead after proj)
  unsigned short* al  = (unsigned short*)(ws + OFF_AL);   // aliases yh/yl region

  prep_all<<<7168, 256, 0, stream>>>(x, y, W1, W2, W3, W4,
                                     xh, xl, yh, yl, w1h, w1l, w2h, w2l, w3h, w3l);
  proj_gemm<<<dim3(32, 4, 3), 256, 0, stream>>>(xh, xl, yh, yl, w1h, w1l, w2h, w2l,
                                                w3h, w3l, qh, ql, kh, kl, vwh, vwl);
  attn_gemm<<<dim3(32, 8), 256, 0, stream>>>(qh, ql, kh, kl, ah, al);
  out_gemm<<<dim3(32, 16), 256, 0, stream>>>(ah, al, vwh, vwl, out);
}